// Round 5
// baseline (35.248 us; speedup 1.0000x reference)
//
#include <hip/hip_runtime.h>

#define NPTS   8192
#define BLOCK  256
#define IPT    2                           // i's per thread (register tile)
#define CHUNKS 128
#define JT     (NPTS / CHUNKS)             // 64 j's per block-chunk

// Phase 1: block (bx, by) computes partial forces for its 512 i's (2/thread)
// over j in [by*JT, (by+1)*JT). Plain coalesced stores to ws — no atomics.
__global__ __launch_bounds__(BLOCK) void nbody_partial(
    const float* __restrict__ pos, float* __restrict__ ws)
{
    const int tid   = threadIdx.x;
    const int ibase = blockIdx.x * (BLOCK * IPT) + tid;
    const int j0    = blockIdx.y * JT;

    float xi[IPT], yi[IPT], zi[IPT], fx[IPT], fy[IPT], fz[IPT];
#pragma unroll
    for (int p = 0; p < IPT; ++p) {
        const int i = ibase + p * BLOCK;
        xi[p] = pos[i * 3 + 0];
        yi[p] = pos[i * 3 + 1];
        zi[p] = pos[i * 3 + 2];
        fx[p] = 0.0f; fy[p] = 0.0f; fz[p] = 0.0f;
    }

    const float4* __restrict__ pos4 = (const float4*)pos;

    // One PAIR = 11 full-rate VALU + 1 rsq. IPT=2 amortizes the (scalarized,
    // block-uniform) j-loads and loop overhead over 2 pairs and gives two
    // independent rsq dependency chains per j.
#define PAIR(p, px, py, pz)                                                 \
    {                                                                       \
        const float dx = xi[p] - (px);                                      \
        const float dy = yi[p] - (py);                                      \
        const float dz = zi[p] - (pz);                                      \
        const float r2  = fmaf(dz, dz, fmaf(dy, dy, fmaf(dx, dx, 1e-12f))); \
        const float ir  = __builtin_amdgcn_rsqf(r2);                        \
        const float ir3 = ir * ir * ir;                                     \
        fx[p] = fmaf(dx, ir3, fx[p]);                                       \
        fy[p] = fmaf(dy, ir3, fy[p]);                                       \
        fz[p] = fmaf(dz, ir3, fz[p]);                                       \
    }
#define PAIR2(px, py, pz) PAIR(0, px, py, pz) PAIR(1, px, py, pz)

    // 4 j-points per 3 uniform float4 loads (s_load_dwordx4, scalar pipe).
#pragma unroll 4
    for (int g = 0; g < JT / 4; ++g) {
        const int base = (j0 / 4 + g) * 3;        // float4 index
        const float4 a = pos4[base + 0];
        const float4 b = pos4[base + 1];
        const float4 c = pos4[base + 2];
        PAIR2(a.x, a.y, a.z);
        PAIR2(a.w, b.x, b.y);
        PAIR2(b.z, b.w, c.x);
        PAIR2(c.y, c.z, c.w);
    }
#undef PAIR2
#undef PAIR

#pragma unroll
    for (int p = 0; p < IPT; ++p) {
        const int i = ibase + p * BLOCK;
        float* o = ws + ((size_t)blockIdx.y * NPTS + i) * 3;
        o[0] = fx[p]; o[1] = fy[p]; o[2] = fz[p];
    }
}

// Phase 2: out[e] = sum over chunks. float4-vectorized, fully coalesced.
__global__ __launch_bounds__(BLOCK) void nbody_reduce(
    const float4* __restrict__ ws, float4* __restrict__ out)
{
    const int e = blockIdx.x * BLOCK + threadIdx.x;   // float4 index, 0..6143
    float4 s = make_float4(0.f, 0.f, 0.f, 0.f);
#pragma unroll 8
    for (int ch = 0; ch < CHUNKS; ++ch) {
        const float4 v = ws[(size_t)ch * (NPTS * 3 / 4) + e];
        s.x += v.x; s.y += v.y; s.z += v.z; s.w += v.w;
    }
    out[e] = s;
}

extern "C" void kernel_launch(void* const* d_in, const int* in_sizes, int n_in,
                              void* d_out, int out_size, void* d_ws, size_t ws_size,
                              hipStream_t stream)
{
    const float* pos = (const float*)d_in[0];

    dim3 grid1(NPTS / (BLOCK * IPT), CHUNKS);   // 16 x 128 = 2048 blocks, 8/CU
    nbody_partial<<<grid1, dim3(BLOCK), 0, stream>>>(pos, (float*)d_ws);

    dim3 grid2(NPTS * 3 / 4 / BLOCK);           // 24 blocks
    nbody_reduce<<<grid2, dim3(BLOCK), 0, stream>>>((const float4*)d_ws,
                                                    (float4*)d_out);
}

// Round 6
// 34.598 us; speedup vs baseline: 1.0188x; 1.0188x over previous
//
#include <hip/hip_runtime.h>

typedef float v2f __attribute__((ext_vector_type(2)));

#define NPTS   8192
#define BLOCK  256
#define CHUNKS 64
#define JT     (NPTS / CHUNKS)       // 128 j's per block-chunk

// ws layout (floats): X[NPTS] | Y[NPTS] | Z[NPTS] | partials[CHUNKS][NPTS][3]
#define WS_POFF (3 * NPTS)

// Pre-pass: AoS pos[i][3] -> SoA X/Y/Z so that packed {x_j, x_{j+1}} is one
// naturally-aligned 8-byte uniform load in the hot loop.
__global__ __launch_bounds__(BLOCK) void soa_pack(
    const float* __restrict__ pos,
    float* __restrict__ X, float* __restrict__ Y, float* __restrict__ Z)
{
    const int t = blockIdx.x * BLOCK + threadIdx.x;
    X[t] = pos[t * 3 + 0];
    Y[t] = pos[t * 3 + 1];
    Z[t] = pos[t * 3 + 2];
}

// Phase 1: block (bx, by) computes partial forces for its 256 i's over
// j in [by*JT, (by+1)*JT), TWO j's per step via packed-fp32 (v_pk_* VOP3P):
// per 2 pairs: 3 pk_sub + 3 pk_fma + 2 v_rsq + 2 pk_mul + 3 pk_fma.
__global__ __launch_bounds__(BLOCK) void nbody_partial(
    const float* __restrict__ X, const float* __restrict__ Y,
    const float* __restrict__ Z, float* __restrict__ part)
{
    const int tid = threadIdx.x;
    const int i   = blockIdx.x * BLOCK + tid;
    const int g0  = blockIdx.y * (JT / 2);     // base 2-j group index

    const float xi = X[i], yi = Y[i], zi = Z[i];
    const v2f xi2 = {xi, xi}, yi2 = {yi, yi}, zi2 = {zi, zi};
    const v2f eps2 = {1e-12f, 1e-12f};
    v2f fx = {0.f, 0.f}, fy = {0.f, 0.f}, fz = {0.f, 0.f};

    const v2f* __restrict__ X2 = (const v2f*)X;
    const v2f* __restrict__ Y2 = (const v2f*)Y;
    const v2f* __restrict__ Z2 = (const v2f*)Z;

#pragma unroll 8
    for (int g = 0; g < JT / 2; ++g) {
        const int u = g0 + g;                  // uniform -> s_load_dwordx2
        const v2f dx = xi2 - X2[u];
        const v2f dy = yi2 - Y2[u];
        const v2f dz = zi2 - Z2[u];
        v2f r2 = dx * dx + eps2;               // fp-contract -> v_pk_fma_f32
        r2 = dy * dy + r2;
        r2 = dz * dz + r2;
        v2f ir;
        ir.x = __builtin_amdgcn_rsqf(r2.x);    // i==j half: r2=1e-12 -> ir3=1e18,
        ir.y = __builtin_amdgcn_rsqf(r2.y);    // dx=0 -> contributes exact 0
        const v2f ir3 = (ir * ir) * ir;
        fx = dx * ir3 + fx;
        fy = dy * ir3 + fy;
        fz = dz * ir3 + fz;
    }

    float* o = part + ((size_t)blockIdx.y * NPTS + i) * 3;
    o[0] = fx.x + fx.y;
    o[1] = fy.x + fy.y;
    o[2] = fz.x + fz.y;
}

// Phase 2: out[e] = sum over chunks. float4-vectorized, fully coalesced.
__global__ __launch_bounds__(BLOCK) void nbody_reduce(
    const float4* __restrict__ part, float4* __restrict__ out)
{
    const int e = blockIdx.x * BLOCK + threadIdx.x;   // float4 index, 0..6143
    float4 s = make_float4(0.f, 0.f, 0.f, 0.f);
#pragma unroll 8
    for (int ch = 0; ch < CHUNKS; ++ch) {
        const float4 v = part[(size_t)ch * (NPTS * 3 / 4) + e];
        s.x += v.x; s.y += v.y; s.z += v.z; s.w += v.w;
    }
    out[e] = s;
}

extern "C" void kernel_launch(void* const* d_in, const int* in_sizes, int n_in,
                              void* d_out, int out_size, void* d_ws, size_t ws_size,
                              hipStream_t stream)
{
    const float* pos = (const float*)d_in[0];
    float* wsf = (float*)d_ws;
    float* X = wsf;
    float* Y = wsf + NPTS;
    float* Z = wsf + 2 * NPTS;
    float* part = wsf + WS_POFF;

    soa_pack<<<dim3(NPTS / BLOCK), dim3(BLOCK), 0, stream>>>(pos, X, Y, Z);

    dim3 grid1(NPTS / BLOCK, CHUNKS);   // 32 x 64 = 2048 blocks, 8/CU
    nbody_partial<<<grid1, dim3(BLOCK), 0, stream>>>(X, Y, Z, part);

    dim3 grid2(NPTS * 3 / 4 / BLOCK);   // 24 blocks
    nbody_reduce<<<grid2, dim3(BLOCK), 0, stream>>>((const float4*)part,
                                                    (float4*)d_out);
}